// Round 14
// baseline (268.896 us; speedup 1.0000x reference)
//
#include <hip/hip_runtime.h>
#include <math.h>

#define T_OBS 256
#define NY 128
#define NITER 150

// ---- gfx9/CDNA DPP wave64 reduction: row_shr 1,2,4,8 + bcast15 + bcast31 ----
#define DPP_ROW_SHR1 0x111
#define DPP_ROW_SHR2 0x112
#define DPP_ROW_SHR4 0x114
#define DPP_ROW_SHR8 0x118
#define DPP_BCAST15  0x142
#define DPP_BCAST31  0x143

#define DPP_ADD_F32(x, ctrl) \
    (x) += __int_as_float(__builtin_amdgcn_update_dpp(0, __float_as_int(x), (ctrl), 0xf, 0xf, true))

// Interleaved dual wave-sum; returns uniform totals in a,b.
__device__ __forceinline__ void wave_sum2(float& a, float& b) {
    DPP_ADD_F32(a, DPP_ROW_SHR1); DPP_ADD_F32(b, DPP_ROW_SHR1);
    DPP_ADD_F32(a, DPP_ROW_SHR2); DPP_ADD_F32(b, DPP_ROW_SHR2);
    DPP_ADD_F32(a, DPP_ROW_SHR4); DPP_ADD_F32(b, DPP_ROW_SHR4);
    DPP_ADD_F32(a, DPP_ROW_SHR8); DPP_ADD_F32(b, DPP_ROW_SHR8);
    DPP_ADD_F32(a, DPP_BCAST15);  DPP_ADD_F32(b, DPP_BCAST15);
    DPP_ADD_F32(a, DPP_BCAST31);  DPP_ADD_F32(b, DPP_BCAST31);
    a = __int_as_float(__builtin_amdgcn_readlane(__float_as_int(a), 63));
    b = __int_as_float(__builtin_amdgcn_readlane(__float_as_int(b), 63));
}

__device__ __forceinline__ float rl(float x, int l) {
    return __int_as_float(__builtin_amdgcn_readlane(__float_as_int(x), l));
}

// Monotonic epoch barrier counter. Never reset: graph replays are
// stream-ordered, so each replay's 256 arrivals occupy one 256-aligned epoch;
// target = (old & ~255) + 256 is uniform across the replay's blocks.
__device__ unsigned g_sync = 0u;

// ---------------- fused kernel: pred(row blk) + device barrier + DRO solve ----------------
// Eliminates the second kernel launch (R13 accounting: ~35-45 us of the 227 us
// total was outside the two compute phases — inter-kernel / graph-node gap).
// Pred phase keeps pred_kernel's exact FP order -> ep/yhat bit-identical.
// DRO body is the verified R7/R11 structure verbatim (local optimum per the
// R2-R12 ledger). yhat for this block is taken from LDS (self-computed);
// ep crosses blocks through the device-scope release/acquire fence pair.
__global__ __launch_bounds__(256, 1)
void fused_kernel(const float* __restrict__ X, const float* __restrict__ Y,
                  const float* __restrict__ W, const float* __restrict__ b,
                  float* __restrict__ yhat_out, float* __restrict__ z_out,
                  float* __restrict__ ep_ws,
                  const float* __restrict__ d_delta, const float* __restrict__ d_gamma) {
    __shared__ float gzp[2][4][NY];              // cross-wave partials, dbuf
    __shared__ __align__(16) float red[2][8];    // cross-wave {S1,S2}, dbuf
    __shared__ float xrow[64];                   // pred: X row
    __shared__ float yhat_lds[NY];               // pred: this block's yhat row

    const int tid  = threadIdx.x;
    const int lane = tid & 63;
    const int wid  = tid >> 6;
    const int blk  = blockIdx.x;

    // ---- pred phase: Y_hat[blk][:] and ep[blk][:] (identical FP order) ----
    if (tid < 64) xrow[tid] = X[blk * 64 + tid];
    __syncthreads();
    if (tid < NY) {
        const float* wr = W + tid * 64;
        float acc = 0.f;
#pragma unroll
        for (int x = 0; x < 64; ++x) acc = fmaf(xrow[x], wr[x], acc);
        const float yh = acc + b[tid];
        yhat_out[blk * NY + tid] = yh;
        yhat_lds[tid] = yh;
        ep_ws[blk * NY + tid] = Y[blk * NY + tid] - yh;
    }
    __syncthreads();

    // ---- device-wide barrier: all 256 ep rows published & visible ----
    if (tid == 0) {
        __threadfence();                                   // release ep row blk
        const unsigned old    = atomicAdd(&g_sync, 1u);    // device-scope
        const unsigned target = (old & ~255u) + 256u;      // this replay's epoch
        while (__hip_atomic_load(&g_sync, __ATOMIC_RELAXED,
                                 __HIP_MEMORY_SCOPE_AGENT) < target) {
            __builtin_amdgcn_s_sleep(2);
        }
        __threadfence();                                   // acquire all ep rows
    }
    __syncthreads();

    // ---- load tiles (R7) ----
    // row layout: thread tid holds ep[tid][0..127] (128 VGPRs)
    float4 rA[32];
    {
        const float4* eg4 = (const float4*)ep_ws + tid * 32;
#pragma unroll
        for (int q = 0; q < 32; ++q) rA[q] = eg4[q];
    }

    // col layout: lane holds ep[tbase+tt][j0..j0+1] (128 VGPRs)
    const int j0    = lane << 1;
    const int tbase = wid << 6;
    float2 rB[64];
#pragma unroll
    for (int tt = 0; tt < 64; ++tt)
        rB[tt] = *(const float2*)(ep_ws + (tbase + tt) * NY + j0);

    const float yh0 = yhat_lds[j0];
    const float yh1 = yhat_lds[j0 + 1];

    // z pair in registers (each wave holds a full redundant copy across lanes)
    float z0 = 1.0f / 128.0f, z1 = 1.0f / 128.0f;
    // warm-start support indicators (carried across iterations)
    float act0 = 1.f, act1 = 1.f;

    const float delta = d_delta[0];
    const float gamma = d_gamma[0];
    float c = 0.f, eta = 0.f, lam = 0.1f;
    int buf = 0;

    for (int k = 0; k < NITER; ++k) {
        const float lr = 0.05f * __builtin_amdgcn_rsqf(1.0f + (float)k);

        // ---- phase A: r_t = ep[t,:].z - c ; z broadcast via readlane ----
        float a0 = 0.f, a1 = 0.f, a2 = 0.f, a3 = 0.f;
#pragma unroll
        for (int q = 0; q < 32; ++q) {
            const float4 e = rA[q];
            const float za = rl(z0, 2 * q);
            const float zb = rl(z1, 2 * q);
            const float zc = rl(z0, 2 * q + 1);
            const float zd = rl(z1, 2 * q + 1);
            a0 = fmaf(e.x, za, a0);
            a1 = fmaf(e.y, zb, a1);
            a2 = fmaf(e.z, zc, a2);
            a3 = fmaf(e.w, zd, a3);
        }
        const float r  = (a0 + a1) + (a2 + a3) - c;
        const float q2 = r * r - eta;
        const float aa = -lam;
        const float st = (q2 > aa) ? 1.0f : ((q2 == aa) ? 0.5f : 0.0f);
        const float wv = st * r;

        // ---- S1/S2 reduction (independent of phase B; scheduler interleaves) ----
        float s1 = st, s2 = wv;
        wave_sum2(s1, s2);
        if (lane == 0) { red[buf][wid * 2] = s1; red[buf][wid * 2 + 1] = s2; }

        // ---- phase B: per-wave partial gz over own 64 rows; w via readlane ----
        float p0 = 0.f, p1 = 0.f, p2 = 0.f, p3 = 0.f;
#pragma unroll
        for (int tt = 0; tt < 64; tt += 2) {
            const float wa = rl(wv, tt);
            const float wb = rl(wv, tt + 1);
            const float2 ea = rB[tt];
            const float2 eb = rB[tt + 1];
            p0 = fmaf(wa, ea.x, p0);
            p1 = fmaf(wa, ea.y, p1);
            p2 = fmaf(wb, eb.x, p2);
            p3 = fmaf(wb, eb.y, p3);
        }
        *(float2*)&gzp[buf][wid][j0] = make_float2(p0 + p2, p1 + p3);

        __syncthreads();   // the ONE barrier: gzp[buf] + red[buf] visible

        // ---- all waves redundantly: scalar updates + z step + projection ----
        const float4 rd0 = *(const float4*)&red[buf][0];
        const float4 rd1 = *(const float4*)&red[buf][4];
        const float S1 = (rd0.x + rd0.z) + (rd1.x + rd1.z);
        const float S2 = (rd0.y + rd0.w) + (rd1.y + rd1.w);
        c   -= lr * (-(2.0f / 256.0f) * S2);
        eta -= lr * (1.0f - S1 * (1.0f / 256.0f));
        lam  = fmaxf(lam - lr * (delta - 1.0f + S1 * (1.0f / 256.0f)), 0.0f);

        const float2 g0v = *(const float2*)&gzp[buf][0][j0];
        const float2 g1v = *(const float2*)&gzp[buf][1][j0];
        const float2 g2v = *(const float2*)&gzp[buf][2][j0];
        const float2 g3v = *(const float2*)&gzp[buf][3][j0];
        const float g0 = (g0v.x + g1v.x) + (g2v.x + g3v.x);
        const float g1 = (g0v.y + g1v.y) + (g2v.y + g3v.y);
        const float v0 = z0 - lr * ((2.0f / 256.0f) * g0 - gamma * yh0);
        const float v1 = z1 - lr * ((2.0f / 256.0f) * g1 - gamma * yh1);

        // ---- simplex projection: ungated thresholding fixed point (R7) ----
        float theta = 0.f;
        for (int m = 0; m < 64; ++m) {
            float s  = act0 * v0 + act1 * v1;
            float cc = act0 + act1;
            wave_sum2(s, cc);
            theta = (s - 1.0f) * __builtin_amdgcn_rcpf(cc);
            const float n0 = (v0 > theta) ? 1.0f : 0.0f;
            const float n1 = (v1 > theta) ? 1.0f : 0.0f;
            const bool changed = (n0 != act0) || (n1 != act1);
            act0 = n0; act1 = n1;
            if (!__any(changed)) break;   // stable support == exact
        }
        z0 = fmaxf(v0 - theta, 0.f);
        z1 = fmaxf(v1 - theta, 0.f);

        buf ^= 1;
    }

    if (wid == 0) *(float2*)&z_out[blk * NY + j0] = make_float2(z0, z1);
}

extern "C" void kernel_launch(void* const* d_in, const int* in_sizes, int n_in,
                              void* d_out, int out_size, void* d_ws, size_t ws_size,
                              hipStream_t stream) {
    const float* X       = (const float*)d_in[0];   // 256*64
    const float* Y       = (const float*)d_in[1];   // 256*128
    const float* W       = (const float*)d_in[2];   // 128*64
    const float* b       = (const float*)d_in[3];   // 128
    const float* d_delta = (const float*)d_in[4];   // 1
    const float* d_gamma = (const float*)d_in[5];   // 1

    float* z_out    = (float*)d_out;                // Z_star: 256*128
    float* yhat_out = z_out + T_OBS * NY;           // Y_hat:  256*128
    float* ep_ws    = (float*)d_ws;                 // 256*128 scratch

    fused_kernel<<<T_OBS, 256, 0, stream>>>(X, Y, W, b, yhat_out, z_out,
                                            ep_ws, d_delta, d_gamma);
}

// Round 15
// 226.540 us; speedup vs baseline: 1.1870x; 1.1870x over previous
//
#include <hip/hip_runtime.h>
#include <math.h>

#define T_OBS 256
#define NY 128
#define NITER 150

// ---- gfx9/CDNA DPP wave64 reduction: row_shr 1,2,4,8 + bcast15 + bcast31 ----
#define DPP_ROW_SHR1 0x111
#define DPP_ROW_SHR2 0x112
#define DPP_ROW_SHR4 0x114
#define DPP_ROW_SHR8 0x118
#define DPP_BCAST15  0x142
#define DPP_BCAST31  0x143

#define DPP_ADD_F32(x, ctrl) \
    (x) += __int_as_float(__builtin_amdgcn_update_dpp(0, __float_as_int(x), (ctrl), 0xf, 0xf, true))

// Interleaved dual wave-sum; returns uniform totals in a,b.
__device__ __forceinline__ void wave_sum2(float& a, float& b) {
    DPP_ADD_F32(a, DPP_ROW_SHR1); DPP_ADD_F32(b, DPP_ROW_SHR1);
    DPP_ADD_F32(a, DPP_ROW_SHR2); DPP_ADD_F32(b, DPP_ROW_SHR2);
    DPP_ADD_F32(a, DPP_ROW_SHR4); DPP_ADD_F32(b, DPP_ROW_SHR4);
    DPP_ADD_F32(a, DPP_ROW_SHR8); DPP_ADD_F32(b, DPP_ROW_SHR8);
    DPP_ADD_F32(a, DPP_BCAST15);  DPP_ADD_F32(b, DPP_BCAST15);
    DPP_ADD_F32(a, DPP_BCAST31);  DPP_ADD_F32(b, DPP_BCAST31);
    a = __int_as_float(__builtin_amdgcn_readlane(__float_as_int(a), 63));
    b = __int_as_float(__builtin_amdgcn_readlane(__float_as_int(b), 63));
}

__device__ __forceinline__ float rl(float x, int l) {
    return __int_as_float(__builtin_amdgcn_readlane(__float_as_int(x), l));
}

// ---------------- kernel 1: Y_hat = X @ W^T + b ; ep = Y - Y_hat ----------------
__global__ __launch_bounds__(128)
void pred_kernel(const float* __restrict__ X, const float* __restrict__ Y,
                 const float* __restrict__ W, const float* __restrict__ b,
                 float* __restrict__ yhat, float* __restrict__ ep) {
    __shared__ float xrow[64];
    const int t = blockIdx.x;
    const int j = threadIdx.x;
    if (j < 64) xrow[j] = X[t * 64 + j];
    __syncthreads();
    const float* wr = W + j * 64;
    float acc = 0.f;
#pragma unroll
    for (int x = 0; x < 64; ++x) acc = fmaf(xrow[x], wr[x], acc);
    const float yh = acc + b[j];
    yhat[t * NY + j] = yh;
    ep[t * NY + j] = Y[t * NY + j] - yh;
}

// ---------------- kernel 2: one DRO solve per block ----------------
// FINAL verified-best structure (R7; re-verified R11/R13 at 227.1-227.4 us
// total): readlane broadcasts on the VALU pipe, ONE barrier per iteration,
// ungated thresholding fixed-point projection. Complete session ledger for
// why this is the measured structural optimum:
//  - R2/R12: >1 wave/SIMD impossible without loss — the 256-VGPR ep tile
//    state forces 1 wave/SIMD (R12: 2 waves/SIMD capped VGPR at 128 and
//    spilled 15 MB to scratch, 2.9x slower; R2: finer split duplicates
//    issue work and adds exchange barriers, +44%).
//  - R3: LDS-pipe broadcasts expose lgkmcnt latency at 1 wave/SIMD (+40%).
//  - R4-R6: register pinning unsupported/aborts/induces v_mov shuffles.
//  - R8: v_pk_fma_f32 is half-rate fp32 on gfx950 — packing gains nothing,
//    and SALU-pack coupling adds hazards (+11%).
//  - R9: ballot/popcount projection adds VALU<->SALU round trips (+16%).
//  - R10: scheduling nudges — compiler schedule already optimal (+4%).
//  - R14: pred+dro fusion with device-wide barrier costs ~40 us in-kernel;
//    the ~45 us outside compute is fixed harness overhead (present with
//    1 kernel too), not inter-kernel gap.
__global__ __launch_bounds__(256, 1)
void dro_kernel(const float* __restrict__ ep_g, const float* __restrict__ yhat_g,
                float* __restrict__ z_out,
                const float* __restrict__ d_delta, const float* __restrict__ d_gamma) {
    __shared__ float gzp[2][4][NY];              // cross-wave partials, dbuf
    __shared__ __align__(16) float red[2][8];    // cross-wave {S1,S2}, dbuf

    const int tid  = threadIdx.x;
    const int lane = tid & 63;
    const int wid  = tid >> 6;
    const int blk  = blockIdx.x;

    // row layout: thread tid holds ep[tid][0..127] (128 VGPRs)
    float4 rA[32];
    {
        const float4* eg4 = (const float4*)ep_g + tid * 32;
#pragma unroll
        for (int q = 0; q < 32; ++q) rA[q] = eg4[q];
    }

    // col layout: lane holds ep[tbase+tt][j0..j0+1] (128 VGPRs)
    const int j0    = lane << 1;
    const int tbase = wid << 6;
    float2 rB[64];
#pragma unroll
    for (int tt = 0; tt < 64; ++tt)
        rB[tt] = *(const float2*)(ep_g + (tbase + tt) * NY + j0);

    const float yh0 = yhat_g[blk * NY + j0];
    const float yh1 = yhat_g[blk * NY + j0 + 1];

    // z pair in registers (each wave holds a full redundant copy across lanes)
    float z0 = 1.0f / 128.0f, z1 = 1.0f / 128.0f;
    // warm-start support indicators (carried across iterations)
    float act0 = 1.f, act1 = 1.f;

    const float delta = d_delta[0];
    const float gamma = d_gamma[0];
    float c = 0.f, eta = 0.f, lam = 0.1f;
    int buf = 0;

    for (int k = 0; k < NITER; ++k) {
        const float lr = 0.05f * __builtin_amdgcn_rsqf(1.0f + (float)k);

        // ---- phase A: r_t = ep[t,:].z - c ; z broadcast via readlane ----
        float a0 = 0.f, a1 = 0.f, a2 = 0.f, a3 = 0.f;
#pragma unroll
        for (int q = 0; q < 32; ++q) {
            const float4 e = rA[q];
            const float za = rl(z0, 2 * q);
            const float zb = rl(z1, 2 * q);
            const float zc = rl(z0, 2 * q + 1);
            const float zd = rl(z1, 2 * q + 1);
            a0 = fmaf(e.x, za, a0);
            a1 = fmaf(e.y, zb, a1);
            a2 = fmaf(e.z, zc, a2);
            a3 = fmaf(e.w, zd, a3);
        }
        const float r  = (a0 + a1) + (a2 + a3) - c;
        const float q2 = r * r - eta;
        const float aa = -lam;
        const float st = (q2 > aa) ? 1.0f : ((q2 == aa) ? 0.5f : 0.0f);
        const float wv = st * r;

        // ---- S1/S2 reduction (independent of phase B; scheduler interleaves) ----
        float s1 = st, s2 = wv;
        wave_sum2(s1, s2);
        if (lane == 0) { red[buf][wid * 2] = s1; red[buf][wid * 2 + 1] = s2; }

        // ---- phase B: per-wave partial gz over own 64 rows; w via readlane ----
        float p0 = 0.f, p1 = 0.f, p2 = 0.f, p3 = 0.f;
#pragma unroll
        for (int tt = 0; tt < 64; tt += 2) {
            const float wa = rl(wv, tt);
            const float wb = rl(wv, tt + 1);
            const float2 ea = rB[tt];
            const float2 eb = rB[tt + 1];
            p0 = fmaf(wa, ea.x, p0);
            p1 = fmaf(wa, ea.y, p1);
            p2 = fmaf(wb, eb.x, p2);
            p3 = fmaf(wb, eb.y, p3);
        }
        *(float2*)&gzp[buf][wid][j0] = make_float2(p0 + p2, p1 + p3);

        __syncthreads();   // the ONE barrier: gzp[buf] + red[buf] visible

        // ---- all waves redundantly: scalar updates + z step + projection ----
        const float4 rd0 = *(const float4*)&red[buf][0];
        const float4 rd1 = *(const float4*)&red[buf][4];
        const float S1 = (rd0.x + rd0.z) + (rd1.x + rd1.z);
        const float S2 = (rd0.y + rd0.w) + (rd1.y + rd1.w);
        c   -= lr * (-(2.0f / 256.0f) * S2);
        eta -= lr * (1.0f - S1 * (1.0f / 256.0f));
        lam  = fmaxf(lam - lr * (delta - 1.0f + S1 * (1.0f / 256.0f)), 0.0f);

        const float2 g0v = *(const float2*)&gzp[buf][0][j0];
        const float2 g1v = *(const float2*)&gzp[buf][1][j0];
        const float2 g2v = *(const float2*)&gzp[buf][2][j0];
        const float2 g3v = *(const float2*)&gzp[buf][3][j0];
        const float g0 = (g0v.x + g1v.x) + (g2v.x + g3v.x);
        const float g1 = (g0v.y + g1v.y) + (g2v.y + g3v.y);
        const float v0 = z0 - lr * ((2.0f / 256.0f) * g0 - gamma * yh0);
        const float v1 = z1 - lr * ((2.0f / 256.0f) * g1 - gamma * yh1);

        // ---- simplex projection: ungated thresholding fixed point.
        // theta from current support S; new S = {v > theta} (reactivation
        // allowed). Stable S == exact KKT support; summation order over the
        // converged S is identical to the gated version -> same theta bits.
        float theta = 0.f;
        for (int m = 0; m < 64; ++m) {
            float s  = act0 * v0 + act1 * v1;
            float cc = act0 + act1;
            wave_sum2(s, cc);
            theta = (s - 1.0f) * __builtin_amdgcn_rcpf(cc);
            const float n0 = (v0 > theta) ? 1.0f : 0.0f;
            const float n1 = (v1 > theta) ? 1.0f : 0.0f;
            const bool changed = (n0 != act0) || (n1 != act1);
            act0 = n0; act1 = n1;
            if (!__any(changed)) break;   // stable support == exact
        }
        z0 = fmaxf(v0 - theta, 0.f);
        z1 = fmaxf(v1 - theta, 0.f);

        buf ^= 1;
    }

    if (wid == 0) *(float2*)&z_out[blk * NY + j0] = make_float2(z0, z1);
}

extern "C" void kernel_launch(void* const* d_in, const int* in_sizes, int n_in,
                              void* d_out, int out_size, void* d_ws, size_t ws_size,
                              hipStream_t stream) {
    const float* X       = (const float*)d_in[0];   // 256*64
    const float* Y       = (const float*)d_in[1];   // 256*128
    const float* W       = (const float*)d_in[2];   // 128*64
    const float* b       = (const float*)d_in[3];   // 128
    const float* d_delta = (const float*)d_in[4];   // 1
    const float* d_gamma = (const float*)d_in[5];   // 1

    float* z_out    = (float*)d_out;                // Z_star: 256*128
    float* yhat_out = z_out + T_OBS * NY;           // Y_hat:  256*128
    float* ep_ws    = (float*)d_ws;                 // 256*128 scratch

    pred_kernel<<<T_OBS, 128, 0, stream>>>(X, Y, W, b, yhat_out, ep_ws);
    dro_kernel<<<T_OBS, 256, 0, stream>>>(ep_ws, yhat_out, z_out, d_delta, d_gamma);
}